// Round 2
// baseline (585.816 us; speedup 1.0000x reference)
//
#include <hip/hip_runtime.h>
#include <hip/hip_bf16.h>

#define DD 128
#define ROWS_PER_BLOCK 16

__device__ __forceinline__ float lo16(unsigned int d) {
    union { unsigned int i; float f; } v; v.i = d << 16; return v.f;
}
__device__ __forceinline__ float hi16(unsigned int d) {
    union { unsigned int i; float f; } v; v.i = d & 0xffff0000u; return v.f;
}
__device__ __forceinline__ float bf2f(unsigned short u) {
    union { unsigned int i; float f; } v; v.i = ((unsigned int)u) << 16; return v.f;
}
__device__ __forceinline__ unsigned short f2bf(float f) {
    union { float f; unsigned int i; } v; v.f = f;
    unsigned int x = v.i;
    return (unsigned short)((x + 0x7fffu + ((x >> 16) & 1u)) >> 16);  // RNE
}

// ---------------------------------------------------------------------------
// Kernel 0: sniff dtypes from data.
// flags[0] = 1 if float arrays are bf16 (low 16 bits of dwords parse as sane
//            bf16 exponents), 0 if fp32.
// flags[1] = 1 if edge_index is int64 (all odd dwords zero), 0 if int32.
// ---------------------------------------------------------------------------
__global__ void gat_sniff(const unsigned int* __restrict__ X,
                          const unsigned int* __restrict__ EI,
                          int* __restrict__ flags)
{
    const int lane = threadIdx.x;  // 64 threads
    const unsigned int d  = X[lane];
    const unsigned int lo = d & 0xffffu;
    const int e = (int)((lo >> 7) & 0xff);
    const int vote_bf  = ((e >= 90 && e <= 140) || (lo & 0x7fffu) == 0) ? 1 : 0;
    const int vote_i64 = (EI[2 * lane + 1] == 0u) ? 1 : 0;
    unsigned long long mb = __ballot(vote_bf);
    unsigned long long mi = __ballot(vote_i64);
    if (lane == 0) {
        flags[0] = (__popcll(mb) >= 48) ? 1 : 0;
        flags[1] = (__popcll(mi) == 64) ? 1 : 0;
    }
}

// ---------------------------------------------------------------------------
// GEMM + self-loop fold, bf16 variant (flags[0]==1)
// ---------------------------------------------------------------------------
__global__ __launch_bounds__(256)
void gat_gemm_bf(const unsigned int* __restrict__ X,      // bf16 pairs [N][64]
                 const unsigned int* __restrict__ W1,
                 const unsigned short* __restrict__ b1,
                 const unsigned int* __restrict__ W2,
                 const unsigned short* __restrict__ b2,
                 const unsigned short* __restrict__ wa1,
                 const unsigned short* __restrict__ ba1,
                 const unsigned short* __restrict__ wa2,
                 const unsigned short* __restrict__ ba2,
                 float* __restrict__ acc,                 // ws fp32 [N][128]
                 unsigned int* __restrict__ fjb,          // ws bf16 pairs [N][64]
                 float* __restrict__ a1g, float* __restrict__ a2g,
                 int N, const int* __restrict__ flags)
{
    if (flags[0] != 1) return;
    const int t = threadIdx.x, wave = t >> 6, lane = t & 63;

    const uint4* wrow = (t < 128) ? ((const uint4*)W1 + t * 16)
                                  : ((const uint4*)W2 + (t - 128) * 16);
    uint4 w[16];
#pragma unroll
    for (int i = 0; i < 16; ++i) w[i] = wrow[i];

    const float bias = bf2f((t < 128) ? b1[t] : b2[t - 128]);
    const float attw = bf2f((t < 128) ? wa1[t] : wa2[t - 128]);
    const float bab1 = bf2f(*ba1), bab2 = bf2f(*ba2);

    __shared__ uint4 xs4[16];
    __shared__ float frow[256];
    __shared__ float red[4];
    __shared__ float attS;

    const int row0 = blockIdx.x * ROWS_PER_BLOCK;
    for (int rr = 0; rr < ROWS_PER_BLOCK; ++rr) {
        const int row = row0 + rr;
        if (row >= N) break;
        __syncthreads();
        if (t < 16) xs4[t] = ((const uint4*)X)[row * 16 + t];
        __syncthreads();

        float s = 0.f;
#pragma unroll
        for (int i = 0; i < 16; ++i) {
            const uint4 wv = w[i], xv = xs4[i];
            s += lo16(wv.x) * lo16(xv.x) + hi16(wv.x) * hi16(xv.x);
            s += lo16(wv.y) * lo16(xv.y) + hi16(wv.y) * hi16(xv.y);
            s += lo16(wv.z) * lo16(xv.z) + hi16(wv.z) * hi16(xv.z);
            s += lo16(wv.w) * lo16(xv.w) + hi16(wv.w) * hi16(xv.w);
        }
        float val = s + bias;
        val = val > 0.f ? val : 0.f;
        frow[t] = val;

        float c = val * attw;
#pragma unroll
        for (int off = 32; off > 0; off >>= 1) c += __shfl_down(c, off);
        if (lane == 0) red[wave] = c;
        __syncthreads();
        if (t == 0) {
            const float A1 = red[0] + red[1] + bab1;
            const float A2 = red[2] + red[3] + bab2;
            a1g[row] = A1; a2g[row] = A2;
            attS = 1.f / (1.f + expf(-(A1 + A2)));
        }
        __syncthreads();
        const float att = attS;

        if (t < 128) {
            acc[(size_t)row * DD + t] = frow[t] + att * frow[128 + t];
        } else if (t < 192) {
            const int idx = t - 128;
            fjb[row * 64 + idx] =
                ((unsigned int)f2bf(frow[129 + 2 * idx]) << 16) |
                (unsigned int)f2bf(frow[128 + 2 * idx]);
        }
    }
}

// ---------------------------------------------------------------------------
// GEMM + self-loop fold, fp32 variant (flags[0]==0); acc == d_out (fp32)
// ---------------------------------------------------------------------------
__global__ __launch_bounds__(256)
void gat_gemm_fp(const float* __restrict__ X,
                 const float* __restrict__ W1, const float* __restrict__ b1,
                 const float* __restrict__ W2, const float* __restrict__ b2,
                 const float* __restrict__ wa1, const float* __restrict__ ba1,
                 const float* __restrict__ wa2, const float* __restrict__ ba2,
                 float* __restrict__ acc,                 // d_out fp32 [N][128]
                 float* __restrict__ fjf,                 // ws fp32 [N][128]
                 float* __restrict__ a1g, float* __restrict__ a2g,
                 int N, const int* __restrict__ flags)
{
    if (flags[0] != 0) return;
    const int t = threadIdx.x, wave = t >> 6, lane = t & 63;

    const float4* wrow = (t < 128) ? ((const float4*)W1 + t * 32)
                                   : ((const float4*)W2 + (t - 128) * 32);
    float4 w[32];
#pragma unroll
    for (int i = 0; i < 32; ++i) w[i] = wrow[i];

    const float bias = (t < 128) ? b1[t] : b2[t - 128];
    const float attw = (t < 128) ? wa1[t] : wa2[t - 128];
    const float bab1 = *ba1, bab2 = *ba2;

    __shared__ float4 xsf[32];
    __shared__ float frow[256];
    __shared__ float red[4];
    __shared__ float attS;

    const int row0 = blockIdx.x * ROWS_PER_BLOCK;
    for (int rr = 0; rr < ROWS_PER_BLOCK; ++rr) {
        const int row = row0 + rr;
        if (row >= N) break;
        __syncthreads();
        if (t < 32) xsf[t] = ((const float4*)X)[row * 32 + t];
        __syncthreads();

        float s = 0.f;
#pragma unroll
        for (int i = 0; i < 32; ++i) {
            const float4 wv = w[i], xv = xsf[i];
            s += wv.x * xv.x + wv.y * xv.y + wv.z * xv.z + wv.w * xv.w;
        }
        float val = s + bias;
        val = val > 0.f ? val : 0.f;
        frow[t] = val;

        float c = val * attw;
#pragma unroll
        for (int off = 32; off > 0; off >>= 1) c += __shfl_down(c, off);
        if (lane == 0) red[wave] = c;
        __syncthreads();
        if (t == 0) {
            const float A1 = red[0] + red[1] + bab1;
            const float A2 = red[2] + red[3] + bab2;
            a1g[row] = A1; a2g[row] = A2;
            attS = 1.f / (1.f + expf(-(A1 + A2)));
        }
        __syncthreads();
        const float att = attS;

        if (t < 128) acc[(size_t)row * DD + t] = frow[t] + att * frow[128 + t];
        else         fjf[(size_t)row * DD + (t - 128)] = frow[t];
    }
}

// ---------------------------------------------------------------------------
// Scatter, bf16 variant: wave per edge, acc in ws
// ---------------------------------------------------------------------------
__global__ __launch_bounds__(256)
void gat_scatter_bf(const int* __restrict__ ei,
                    const float* __restrict__ a1, const float* __restrict__ a2,
                    const unsigned int* __restrict__ fjb,
                    float* __restrict__ acc,
                    int nEdges, int N, const int* __restrict__ flags)
{
    if (flags[0] != 1) return;
    const int i64  = flags[1];
    const int lane = threadIdx.x & 63;
    const int wid  = (blockIdx.x * blockDim.x + threadIdx.x) >> 6;
    const int nw   = (gridDim.x * blockDim.x) >> 6;

    for (int e = wid; e < nEdges; e += nw) {
        const int r = i64 ? ei[2 * e]                : ei[e];
        const int c = i64 ? ei[2 * (nEdges + e)]     : ei[nEdges + e];
        if ((unsigned)r >= (unsigned)N || (unsigned)c >= (unsigned)N) continue;
        float att = a1[r] + a2[c];
        att = 1.f / (1.f + expf(-att));
        const unsigned int d = fjb[c * 64 + lane];
        atomicAdd(&acc[(size_t)r * DD + 2 * lane],     lo16(d) * att);
        atomicAdd(&acc[(size_t)r * DD + 2 * lane + 1], hi16(d) * att);
    }
}

// ---------------------------------------------------------------------------
// Scatter, fp32 variant: wave per edge, acc == d_out
// ---------------------------------------------------------------------------
__global__ __launch_bounds__(256)
void gat_scatter_fp(const int* __restrict__ ei,
                    const float* __restrict__ a1, const float* __restrict__ a2,
                    const float* __restrict__ fjf,
                    float* __restrict__ acc,
                    int nEdges, int N, const int* __restrict__ flags)
{
    if (flags[0] != 0) return;
    const int i64  = flags[1];
    const int lane = threadIdx.x & 63;
    const int wid  = (blockIdx.x * blockDim.x + threadIdx.x) >> 6;
    const int nw   = (gridDim.x * blockDim.x) >> 6;

    for (int e = wid; e < nEdges; e += nw) {
        const int r = i64 ? ei[2 * e]                : ei[e];
        const int c = i64 ? ei[2 * (nEdges + e)]     : ei[nEdges + e];
        if ((unsigned)r >= (unsigned)N || (unsigned)c >= (unsigned)N) continue;
        float att = a1[r] + a2[c];
        att = 1.f / (1.f + expf(-att));
        const float v0 = fjf[(size_t)c * DD + lane];
        const float v1 = fjf[(size_t)c * DD + 64 + lane];
        atomicAdd(&acc[(size_t)r * DD + lane],      v0 * att);
        atomicAdd(&acc[(size_t)r * DD + 64 + lane], v1 * att);
    }
}

// ---------------------------------------------------------------------------
// Convert (bf16 variant only): ws fp32 acc -> bf16 d_out
// ---------------------------------------------------------------------------
__global__ __launch_bounds__(256)
void gat_convert(const float4* __restrict__ acc, ushort4* __restrict__ out,
                 int n4, const int* __restrict__ flags)
{
    if (flags[0] != 1) return;
    const int i = blockIdx.x * blockDim.x + threadIdx.x;
    if (i < n4) {
        const float4 v = acc[i];
        ushort4 o;
        o.x = f2bf(v.x); o.y = f2bf(v.y); o.z = f2bf(v.z); o.w = f2bf(v.w);
        out[i] = o;
    }
}

extern "C" void kernel_launch(void* const* d_in, const int* in_sizes, int n_in,
                              void* d_out, int out_size, void* d_ws, size_t ws_size,
                              hipStream_t stream)
{
    const void* X   = d_in[0];
    const void* W1  = d_in[1];
    const void* b1  = d_in[2];
    const void* W2  = d_in[3];
    const void* b2  = d_in[4];
    const void* wa1 = d_in[5];
    const void* ba1 = d_in[6];
    const void* wa2 = d_in[7];
    const void* ba2 = d_in[8];
    const int*  ei  = (const int*)d_in[9];

    const int N = in_sizes[0] / DD;
    const int E = in_sizes[9] / 2;

    // ws layout: [flags 256B][region1: N*128 fp32][region2: N*64 dwords][a1][a2]
    int*   flags = (int*)d_ws;
    char*  base  = (char*)d_ws + 256;
    float* accWs = (float*)base;                                   // bf16 path acc
    float* fjf   = (float*)base;                                   // fp32 path fj
    unsigned int* fjb = (unsigned int*)(base + (size_t)N * DD * 4);
    float* a1 = (float*)(base + (size_t)N * DD * 4 + (size_t)N * DD * 2);
    float* a2 = a1 + N;

    gat_sniff<<<1, 64, 0, stream>>>((const unsigned int*)X, (const unsigned int*)ei, flags);

    const int nblk1 = (N + ROWS_PER_BLOCK - 1) / ROWS_PER_BLOCK;
    gat_gemm_bf<<<nblk1, 256, 0, stream>>>(
        (const unsigned int*)X, (const unsigned int*)W1, (const unsigned short*)b1,
        (const unsigned int*)W2, (const unsigned short*)b2,
        (const unsigned short*)wa1, (const unsigned short*)ba1,
        (const unsigned short*)wa2, (const unsigned short*)ba2,
        accWs, fjb, a1, a2, N, flags);
    gat_gemm_fp<<<nblk1, 256, 0, stream>>>(
        (const float*)X, (const float*)W1, (const float*)b1,
        (const float*)W2, (const float*)b2,
        (const float*)wa1, (const float*)ba1, (const float*)wa2, (const float*)ba2,
        (float*)d_out, fjf, a1, a2, N, flags);

    gat_scatter_bf<<<2048, 256, 0, stream>>>(ei, a1, a2, fjb, accWs, E, N, flags);
    gat_scatter_fp<<<2048, 256, 0, stream>>>(ei, a1, a2, fjf, (float*)d_out, E, N, flags);

    const int n4 = N * DD / 4;
    gat_convert<<<(n4 + 255) / 256, 256, 0, stream>>>(
        (const float4*)accWs, (ushort4*)d_out, n4, flags);
}

// Round 3
// 476.615 us; speedup vs baseline: 1.2291x; 1.2291x over previous
//
#include <hip/hip_runtime.h>
#include <hip/hip_bf16.h>

#define DD 128
#define ROWS_PER_BLOCK 16

// ---------------------------------------------------------------------------
// Kernel 0: sniff edge-index width. flags[1]=1 if int64 (odd dwords all 0).
// ---------------------------------------------------------------------------
__global__ void gat_sniff(const unsigned int* __restrict__ EI, int* __restrict__ flags)
{
    const int lane = threadIdx.x;  // 64 threads
    const int vote_i64 = (EI[2 * lane + 1] == 0u) ? 1 : 0;
    unsigned long long mi = __ballot(vote_i64);
    if (lane == 0) flags[1] = (__popcll(mi) == 64) ? 1 : 0;
}

// ---------------------------------------------------------------------------
// Kernel 1: zero deg[0..N] and pos[0..N-1]
// ---------------------------------------------------------------------------
__global__ __launch_bounds__(256)
void gat_zero(int* __restrict__ deg, int* __restrict__ pos, int N)
{
    const int i = blockIdx.x * blockDim.x + threadIdx.x;
    if (i <= N) deg[i] = 0;
    if (i < N)  pos[i] = 0;
}

// ---------------------------------------------------------------------------
// Kernel 2: GEMM + self-loop fold (fp32).
//   out  = fi + sigmoid(a1+a2)*fj   (self-loop term)
//   fjf  = fj, a1g/a2g per row
// ---------------------------------------------------------------------------
__global__ __launch_bounds__(256)
void gat_gemm_fp(const float* __restrict__ X,
                 const float* __restrict__ W1, const float* __restrict__ b1,
                 const float* __restrict__ W2, const float* __restrict__ b2,
                 const float* __restrict__ wa1, const float* __restrict__ ba1,
                 const float* __restrict__ wa2, const float* __restrict__ ba2,
                 float* __restrict__ out,                 // d_out fp32 [N][128]
                 float* __restrict__ fjf,                 // ws fp32 [N][128]
                 float* __restrict__ a1g, float* __restrict__ a2g,
                 int N)
{
    const int t = threadIdx.x, wave = t >> 6, lane = t & 63;

    const float4* wrow = (t < 128) ? ((const float4*)W1 + t * 32)
                                   : ((const float4*)W2 + (t - 128) * 32);
    float4 w[32];
#pragma unroll
    for (int i = 0; i < 32; ++i) w[i] = wrow[i];

    const float bias = (t < 128) ? b1[t] : b2[t - 128];
    const float attw = (t < 128) ? wa1[t] : wa2[t - 128];
    const float bab1 = *ba1, bab2 = *ba2;

    __shared__ float4 xsf[32];
    __shared__ float frow[256];
    __shared__ float red[4];
    __shared__ float attS;

    const int row0 = blockIdx.x * ROWS_PER_BLOCK;
    for (int rr = 0; rr < ROWS_PER_BLOCK; ++rr) {
        const int row = row0 + rr;
        if (row >= N) break;
        __syncthreads();
        if (t < 32) xsf[t] = ((const float4*)X)[row * 32 + t];
        __syncthreads();

        float s = 0.f;
#pragma unroll
        for (int i = 0; i < 32; ++i) {
            const float4 wv = w[i], xv = xsf[i];
            s += wv.x * xv.x + wv.y * xv.y + wv.z * xv.z + wv.w * xv.w;
        }
        float val = s + bias;
        val = val > 0.f ? val : 0.f;
        frow[t] = val;

        float c = val * attw;
#pragma unroll
        for (int off = 32; off > 0; off >>= 1) c += __shfl_down(c, off);
        if (lane == 0) red[wave] = c;
        __syncthreads();
        if (t == 0) {
            const float A1 = red[0] + red[1] + bab1;
            const float A2 = red[2] + red[3] + bab2;
            a1g[row] = A1; a2g[row] = A2;
            attS = 1.f / (1.f + expf(-(A1 + A2)));
        }
        __syncthreads();
        const float att = attS;

        if (t < 128) out[(size_t)row * DD + t] = frow[t] + att * frow[128 + t];
        else         fjf[(size_t)row * DD + (t - 128)] = frow[t];
    }
}

// ---------------------------------------------------------------------------
// Kernel 3: histogram of destination rows
// ---------------------------------------------------------------------------
__global__ __launch_bounds__(256)
void gat_hist(const int* __restrict__ ei, int* __restrict__ deg,
              int nEdges, int N, const int* __restrict__ flags)
{
    const int i64 = flags[1];
    const int tid = blockIdx.x * blockDim.x + threadIdx.x;
    const int nth = gridDim.x * blockDim.x;
    for (int e = tid; e < nEdges; e += nth) {
        int r = i64 ? ei[2 * e] : ei[e];
        if ((unsigned)r >= (unsigned)N) r = 0;   // defensive clamp
        atomicAdd(&deg[r], 1);
    }
}

// ---------------------------------------------------------------------------
// Kernel 4: exclusive prefix scan of deg -> offs (single block, 256 threads)
// ---------------------------------------------------------------------------
__global__ __launch_bounds__(256)
void gat_scan(const int* __restrict__ deg, int* __restrict__ offs, int N)
{
    __shared__ int wsum[4];
    const int t = threadIdx.x, lane = t & 63, wv = t >> 6;
    int carry = 0;
    const int CH = 256 * 8;
    for (int base = 0; base < N; base += CH) {
        const int idx0 = base + t * 8;
        int v[8];
#pragma unroll
        for (int i = 0; i < 8; ++i) {
            const int idx = idx0 + i;
            v[i] = (idx < N) ? deg[idx] : 0;
        }
        int s = 0;
#pragma unroll
        for (int i = 0; i < 8; ++i) s += v[i];
        // wave-inclusive scan of s
        int sc = s;
#pragma unroll
        for (int off = 1; off < 64; off <<= 1) {
            const int o = __shfl_up(sc, off);
            if (lane >= off) sc += o;
        }
        if (lane == 63) wsum[wv] = sc;
        __syncthreads();
        int wpre = 0;
        for (int i = 0; i < wv; ++i) wpre += wsum[i];
        int run = carry + wpre + (sc - s);
#pragma unroll
        for (int i = 0; i < 8; ++i) {
            const int idx = idx0 + i;
            if (idx < N) offs[idx] = run;
            run += v[i];
        }
        const int tot = wsum[0] + wsum[1] + wsum[2] + wsum[3];
        __syncthreads();   // wsum consumed before next iteration overwrites
        carry += tot;
    }
    if (t == 0) offs[N] = carry;
}

// ---------------------------------------------------------------------------
// Kernel 5: bucket-scatter cols into CSR order
// ---------------------------------------------------------------------------
__global__ __launch_bounds__(256)
void gat_bucket(const int* __restrict__ ei, const int* __restrict__ offs,
                int* __restrict__ pos, int* __restrict__ colPerm,
                int nEdges, int N, const int* __restrict__ flags)
{
    const int i64 = flags[1];
    const int tid = blockIdx.x * blockDim.x + threadIdx.x;
    const int nth = gridDim.x * blockDim.x;
    for (int e = tid; e < nEdges; e += nth) {
        int r = i64 ? ei[2 * e]            : ei[e];
        int c = i64 ? ei[2 * (nEdges + e)] : ei[nEdges + e];
        if ((unsigned)r >= (unsigned)N) r = 0;
        if ((unsigned)c >= (unsigned)N) c = 0;
        const int slot = offs[r] + atomicAdd(&pos[r], 1);
        colPerm[slot] = c;
    }
}

// ---------------------------------------------------------------------------
// Kernel 6: atomic-free accumulate. One wave per destination row.
//   out[row] += sum_e sigmoid(a1[row]+a2[col_e]) * fj[col_e]
// ---------------------------------------------------------------------------
__global__ __launch_bounds__(256)
void gat_accum(const int* __restrict__ offs, const int* __restrict__ colPerm,
               const float* __restrict__ a1, const float* __restrict__ a2,
               const float* __restrict__ fjf, float* __restrict__ out, int N)
{
    const int lane = threadIdx.x & 63;
    const int row  = (blockIdx.x * blockDim.x + threadIdx.x) >> 6;
    if (row >= N) return;

    const int start = offs[row], end = offs[row + 1];
    const float a1r = a1[row];
    float ax = 0.f, ay = 0.f;
    for (int e = start; e < end; ++e) {
        const int col = colPerm[e];
        const float att = 1.f / (1.f + expf(-(a1r + a2[col])));
        const float2 v = *(const float2*)&fjf[(size_t)col * DD + 2 * lane];
        ax += att * v.x;
        ay += att * v.y;
    }
    float2* op = (float2*)&out[(size_t)row * DD + 2 * lane];
    float2 cur = *op;
    cur.x += ax; cur.y += ay;
    *op = cur;
}

extern "C" void kernel_launch(void* const* d_in, const int* in_sizes, int n_in,
                              void* d_out, int out_size, void* d_ws, size_t ws_size,
                              hipStream_t stream)
{
    const float* X   = (const float*)d_in[0];
    const float* W1  = (const float*)d_in[1];
    const float* b1  = (const float*)d_in[2];
    const float* W2  = (const float*)d_in[3];
    const float* b2  = (const float*)d_in[4];
    const float* wa1 = (const float*)d_in[5];
    const float* ba1 = (const float*)d_in[6];
    const float* wa2 = (const float*)d_in[7];
    const float* ba2 = (const float*)d_in[8];
    const int*   ei  = (const int*)d_in[9];

    const int N = in_sizes[0] / DD;
    const int E = in_sizes[9] / 2;

    // ws layout: [flags 256B][fjf N*128 f32][a1 N][a2 N][deg N+1][offs N+1][pos N][colPerm E]
    int*   flags = (int*)d_ws;
    char*  base  = (char*)d_ws + 256;
    float* fjf   = (float*)base;
    float* a1    = (float*)(base + (size_t)N * DD * 4);
    float* a2    = a1 + N;
    int*   deg   = (int*)(a2 + N);
    int*   offs  = deg + (N + 1);
    int*   pos   = offs + (N + 1);
    int*   colPerm = pos + N;

    gat_sniff<<<1, 64, 0, stream>>>((const unsigned int*)ei, flags);
    gat_zero<<<(N + 256) / 256, 256, 0, stream>>>(deg, pos, N);

    const int nblk1 = (N + ROWS_PER_BLOCK - 1) / ROWS_PER_BLOCK;
    gat_gemm_fp<<<nblk1, 256, 0, stream>>>(X, W1, b1, W2, b2, wa1, ba1, wa2, ba2,
                                           (float*)d_out, fjf, a1, a2, N);

    gat_hist<<<1024, 256, 0, stream>>>(ei, deg, E, N, flags);
    gat_scan<<<1, 256, 0, stream>>>(deg, offs, N);
    gat_bucket<<<1024, 256, 0, stream>>>(ei, offs, pos, colPerm, E, N, flags);

    const int nblkA = (N * 64 + 255) / 256;
    gat_accum<<<nblkA, 256, 0, stream>>>(offs, colPerm, a1, a2, fjf, (float*)d_out, N);
}

// Round 4
// 316.436 us; speedup vs baseline: 1.8513x; 1.5062x over previous
//
#include <hip/hip_runtime.h>
#include <hip/hip_bf16.h>

#define DD 128

typedef __bf16 bf16x8 __attribute__((ext_vector_type(8)));
typedef unsigned short u16x8 __attribute__((ext_vector_type(8)));
typedef float f32x4 __attribute__((ext_vector_type(4)));

__device__ __forceinline__ float lo16(unsigned int d) {
    union { unsigned int i; float f; } v; v.i = d << 16; return v.f;
}
__device__ __forceinline__ float hi16(unsigned int d) {
    union { unsigned int i; float f; } v; v.i = d & 0xffff0000u; return v.f;
}
__device__ __forceinline__ unsigned short f2bf(float f) {
    union { float f; unsigned int i; } v; v.f = f;
    unsigned int x = v.i;
    return (unsigned short)((x + 0x7fffu + ((x >> 16) & 1u)) >> 16);  // RNE
}

// ---------------------------------------------------------------------------
// Kernel 0: sniff edge-index width. flags[1]=1 if int64 (odd dwords all 0).
// ---------------------------------------------------------------------------
__global__ void gat_sniff(const unsigned int* __restrict__ EI, int* __restrict__ flags)
{
    const int lane = threadIdx.x;
    const int vote_i64 = (EI[2 * lane + 1] == 0u) ? 1 : 0;
    unsigned long long mi = __ballot(vote_i64);
    if (lane == 0) flags[1] = (__popcll(mi) == 64) ? 1 : 0;
}

__global__ __launch_bounds__(256)
void gat_zero(int* __restrict__ deg, int* __restrict__ pos, int N)
{
    const int i = blockIdx.x * blockDim.x + threadIdx.x;
    if (i <= N) deg[i] = 0;
    if (i < N)  pos[i] = 0;
}

// ---------------------------------------------------------------------------
// MFMA GEMM: one block = 64 rows x 256 cols (fi|fj), K=128, bf16 inputs.
//   out  = fi + sigmoid(a1+a2)*fj   (self-loop term), fp32
//   fjb  = fj packed bf16 pairs [N][64]
// ---------------------------------------------------------------------------
__global__ __launch_bounds__(256)
void gat_gemm_mfma(const float* __restrict__ X,
                   const float* __restrict__ W1, const float* __restrict__ b1,
                   const float* __restrict__ W2, const float* __restrict__ b2,
                   const float* __restrict__ wa1, const float* __restrict__ ba1,
                   const float* __restrict__ wa2, const float* __restrict__ ba2,
                   float* __restrict__ out, unsigned int* __restrict__ fjb,
                   float* __restrict__ a1g, float* __restrict__ a2g, int N)
{
    const int t = threadIdx.x, wave = t >> 6, lane = t & 63;
    const int quad = lane >> 4, l15 = lane & 15;
    const int rowbase = blockIdx.x * 64;

    __shared__ unsigned short At[64 * 136];   // bf16, padded stride (272 B)
    __shared__ float fjL[64 * 132];           // fj fp32, padded
    __shared__ float parts[4][64];
    __shared__ float attL[64];

    const float bab1 = *ba1, bab2 = *ba2;

    // ---- B preload: 16 frags (4 col-tiles x 4 k-steps), stays in VGPRs ----
    bf16x8 bf[4][4];
    float biasv[4], attwv[4];
#pragma unroll
    for (int ct = 0; ct < 4; ++ct) {
        const int n = wave * 64 + ct * 16 + l15;
        const float* wr = (n < 128) ? (W1 + (size_t)n * 128) : (W2 + (size_t)(n - 128) * 128);
        biasv[ct] = (n < 128) ? b1[n] : b2[n - 128];
        attwv[ct] = (n < 128) ? wa1[n] : wa2[n - 128];
#pragma unroll
        for (int ks = 0; ks < 4; ++ks) {
            const int k0 = ks * 32 + quad * 8;
            const float4 u = *(const float4*)(wr + k0);
            const float4 v = *(const float4*)(wr + k0 + 4);
            u16x8 s;
            s[0] = f2bf(u.x); s[1] = f2bf(u.y); s[2] = f2bf(u.z); s[3] = f2bf(u.w);
            s[4] = f2bf(v.x); s[5] = f2bf(v.y); s[6] = f2bf(v.z); s[7] = f2bf(v.w);
            bf[ct][ks] = __builtin_bit_cast(bf16x8, s);
        }
    }

    // ---- stage A-tile: X fp32 -> bf16 LDS ----
    {
        const int r = t >> 2, q = t & 3;
        const int grow = rowbase + r;
#pragma unroll
        for (int i = 0; i < 8; ++i) {
            const int c = q * 32 + i * 4;
            float4 xv = make_float4(0.f, 0.f, 0.f, 0.f);
            if (grow < N) xv = *(const float4*)(X + (size_t)grow * DD + c);
            uint2 p;
            p.x = ((unsigned)f2bf(xv.y) << 16) | f2bf(xv.x);
            p.y = ((unsigned)f2bf(xv.w) << 16) | f2bf(xv.z);
            *(uint2*)&At[r * 136 + c] = p;
        }
    }
    __syncthreads();

    // ---- MFMA main: 64 MFMAs per wave ----
    f32x4 acc[4][4];
#pragma unroll
    for (int rt = 0; rt < 4; ++rt)
#pragma unroll
        for (int ct = 0; ct < 4; ++ct)
            acc[rt][ct] = (f32x4){0.f, 0.f, 0.f, 0.f};

#pragma unroll
    for (int ks = 0; ks < 4; ++ks) {
#pragma unroll
        for (int rt = 0; rt < 4; ++rt) {
            const bf16x8 af = *(const bf16x8*)&At[(rt * 16 + l15) * 136 + ks * 32 + quad * 8];
#pragma unroll
            for (int ct = 0; ct < 4; ++ct)
                acc[rt][ct] = __builtin_amdgcn_mfma_f32_16x16x32_bf16(af, bf[ct][ks], acc[rt][ct], 0, 0, 0);
        }
    }

    // ---- bias + relu in-register ----
#pragma unroll
    for (int rt = 0; rt < 4; ++rt)
#pragma unroll
        for (int ct = 0; ct < 4; ++ct)
#pragma unroll
            for (int reg = 0; reg < 4; ++reg) {
                float v = acc[rt][ct][reg] + biasv[ct];
                acc[rt][ct][reg] = v > 0.f ? v : 0.f;
            }

    // waves 2,3: stash fj into LDS
    if (wave >= 2) {
#pragma unroll
        for (int rt = 0; rt < 4; ++rt)
#pragma unroll
            for (int ct = 0; ct < 4; ++ct)
#pragma unroll
                for (int reg = 0; reg < 4; ++reg) {
                    const int row = rt * 16 + quad * 4 + reg;
                    const int col = (wave - 2) * 64 + ct * 16 + l15;
                    fjL[row * 132 + col] = acc[rt][ct][reg];
                }
    }

    // per-row attention dots (in-register, shfl reduce over 16 lanes)
#pragma unroll
    for (int rt = 0; rt < 4; ++rt) {
#pragma unroll
        for (int reg = 0; reg < 4; ++reg) {
            float p = acc[rt][0][reg] * attwv[0] + acc[rt][1][reg] * attwv[1]
                    + acc[rt][2][reg] * attwv[2] + acc[rt][3][reg] * attwv[3];
            p += __shfl_xor(p, 1);
            p += __shfl_xor(p, 2);
            p += __shfl_xor(p, 4);
            p += __shfl_xor(p, 8);
            if (l15 == 0) parts[wave][rt * 16 + quad * 4 + reg] = p;
        }
    }
    __syncthreads();

    if (t < 64) {
        const float A1 = parts[0][t] + parts[1][t] + bab1;
        const float A2 = parts[2][t] + parts[3][t] + bab2;
        attL[t] = 1.f / (1.f + expf(-(A1 + A2)));
        const int grow = rowbase + t;
        if (grow < N) { a1g[grow] = A1; a2g[grow] = A2; }
    }
    __syncthreads();

    if (wave < 2) {
        // out = fi + att*fj
#pragma unroll
        for (int rt = 0; rt < 4; ++rt)
#pragma unroll
            for (int ct = 0; ct < 4; ++ct)
#pragma unroll
                for (int reg = 0; reg < 4; ++reg) {
                    const int row = rt * 16 + quad * 4 + reg;
                    const int col = wave * 64 + ct * 16 + l15;
                    const int grow = rowbase + row;
                    if (grow < N)
                        out[(size_t)grow * DD + col] =
                            acc[rt][ct][reg] + attL[row] * fjL[row * 132 + col];
                }
    } else {
        // pack fj -> bf16 pairs, coalesced
#pragma unroll 4
        for (int i = 0; i < 32; ++i) {
            const int idx = (wave - 2) * 2048 + i * 64 + lane;
            const int row = idx >> 6, d = idx & 63;
            const int grow = rowbase + row;
            if (grow < N) {
                const float lo = fjL[row * 132 + 2 * d];
                const float hi = fjL[row * 132 + 2 * d + 1];
                fjb[(size_t)grow * 64 + d] = ((unsigned)f2bf(hi) << 16) | f2bf(lo);
            }
        }
    }
}

// ---------------------------------------------------------------------------
// CSR build
// ---------------------------------------------------------------------------
__global__ __launch_bounds__(256)
void gat_hist(const int* __restrict__ ei, int* __restrict__ deg,
              int nEdges, int N, const int* __restrict__ flags)
{
    const int i64 = flags[1];
    const int tid = blockIdx.x * blockDim.x + threadIdx.x;
    const int nth = gridDim.x * blockDim.x;
    for (int e = tid; e < nEdges; e += nth) {
        int r = i64 ? ei[2 * e] : ei[e];
        if ((unsigned)r >= (unsigned)N) r = 0;
        atomicAdd(&deg[r], 1);
    }
}

__global__ __launch_bounds__(256)
void gat_scan(const int* __restrict__ deg, int* __restrict__ offs, int N)
{
    __shared__ int wsum[4];
    const int t = threadIdx.x, lane = t & 63, wv = t >> 6;
    int carry = 0;
    const int CH = 256 * 8;
    for (int base = 0; base < N; base += CH) {
        const int idx0 = base + t * 8;
        int v[8];
#pragma unroll
        for (int i = 0; i < 8; ++i) {
            const int idx = idx0 + i;
            v[i] = (idx < N) ? deg[idx] : 0;
        }
        int s = 0;
#pragma unroll
        for (int i = 0; i < 8; ++i) s += v[i];
        int sc = s;
#pragma unroll
        for (int off = 1; off < 64; off <<= 1) {
            const int o = __shfl_up(sc, off);
            if (lane >= off) sc += o;
        }
        if (lane == 63) wsum[wv] = sc;
        __syncthreads();
        int wpre = 0;
        for (int i = 0; i < wv; ++i) wpre += wsum[i];
        int run = carry + wpre + (sc - s);
#pragma unroll
        for (int i = 0; i < 8; ++i) {
            const int idx = idx0 + i;
            if (idx < N) offs[idx] = run;
            run += v[i];
        }
        const int tot = wsum[0] + wsum[1] + wsum[2] + wsum[3];
        __syncthreads();
        carry += tot;
    }
    if (t == 0) offs[N] = carry;
}

__global__ __launch_bounds__(256)
void gat_bucket(const int* __restrict__ ei, const int* __restrict__ offs,
                int* __restrict__ pos, int* __restrict__ colPerm,
                int nEdges, int N, const int* __restrict__ flags)
{
    const int i64 = flags[1];
    const int tid = blockIdx.x * blockDim.x + threadIdx.x;
    const int nth = gridDim.x * blockDim.x;
    for (int e = tid; e < nEdges; e += nth) {
        int r = i64 ? ei[2 * e]            : ei[e];
        int c = i64 ? ei[2 * (nEdges + e)] : ei[nEdges + e];
        if ((unsigned)r >= (unsigned)N) r = 0;
        if ((unsigned)c >= (unsigned)N) c = 0;
        const int slot = offs[r] + atomicAdd(&pos[r], 1);
        colPerm[slot] = c;
    }
}

// ---------------------------------------------------------------------------
// Accumulate: one wave per row, bf16 gathers, 4 edges in flight
// ---------------------------------------------------------------------------
__global__ __launch_bounds__(256)
void gat_accum(const int* __restrict__ offs, const int* __restrict__ colPerm,
               const float* __restrict__ a1, const float* __restrict__ a2,
               const unsigned int* __restrict__ fjb, float* __restrict__ out, int N)
{
    const int lane = threadIdx.x & 63;
    const int row  = (blockIdx.x * blockDim.x + threadIdx.x) >> 6;
    if (row >= N) return;

    const int start = offs[row], end = offs[row + 1];
    const float a1r = a1[row];
    float ax = 0.f, ay = 0.f;
    int e = start;
    for (; e + 4 <= end; e += 4) {
        const int c0 = colPerm[e],     c1 = colPerm[e + 1];
        const int c2 = colPerm[e + 2], c3 = colPerm[e + 3];
        const float s0 = a2[c0], s1 = a2[c1], s2 = a2[c2], s3 = a2[c3];
        const unsigned d0 = fjb[(size_t)c0 * 64 + lane];
        const unsigned d1 = fjb[(size_t)c1 * 64 + lane];
        const unsigned d2 = fjb[(size_t)c2 * 64 + lane];
        const unsigned d3 = fjb[(size_t)c3 * 64 + lane];
        const float t0 = 1.f / (1.f + expf(-(a1r + s0)));
        const float t1 = 1.f / (1.f + expf(-(a1r + s1)));
        const float t2 = 1.f / (1.f + expf(-(a1r + s2)));
        const float t3 = 1.f / (1.f + expf(-(a1r + s3)));
        ax += t0 * lo16(d0) + t1 * lo16(d1) + t2 * lo16(d2) + t3 * lo16(d3);
        ay += t0 * hi16(d0) + t1 * hi16(d1) + t2 * hi16(d2) + t3 * hi16(d3);
    }
    for (; e < end; ++e) {
        const int c = colPerm[e];
        const float att = 1.f / (1.f + expf(-(a1r + a2[c])));
        const unsigned d = fjb[(size_t)c * 64 + lane];
        ax += att * lo16(d);
        ay += att * hi16(d);
    }
    float2* op = (float2*)&out[(size_t)row * DD + 2 * lane];
    float2 cur = *op;
    cur.x += ax; cur.y += ay;
    *op = cur;
}

extern "C" void kernel_launch(void* const* d_in, const int* in_sizes, int n_in,
                              void* d_out, int out_size, void* d_ws, size_t ws_size,
                              hipStream_t stream)
{
    const float* X   = (const float*)d_in[0];
    const float* W1  = (const float*)d_in[1];
    const float* b1  = (const float*)d_in[2];
    const float* W2  = (const float*)d_in[3];
    const float* b2  = (const float*)d_in[4];
    const float* wa1 = (const float*)d_in[5];
    const float* ba1 = (const float*)d_in[6];
    const float* wa2 = (const float*)d_in[7];
    const float* ba2 = (const float*)d_in[8];
    const int*   ei  = (const int*)d_in[9];

    const int N = in_sizes[0] / DD;
    const int E = in_sizes[9] / 2;

    // ws: [flags 256B][fjb N*64 u32][a1 N][a2 N][deg N+1][offs N+1][pos N][colPerm E]
    int*   flags = (int*)d_ws;
    char*  base  = (char*)d_ws + 256;
    unsigned int* fjb = (unsigned int*)base;
    float* a1    = (float*)(base + (size_t)N * 64 * 4);
    float* a2    = a1 + N;
    int*   deg   = (int*)(a2 + N);
    int*   offs  = deg + (N + 1);
    int*   pos   = offs + (N + 1);
    int*   colPerm = pos + N;

    gat_sniff<<<1, 64, 0, stream>>>((const unsigned int*)ei, flags);
    gat_zero<<<(N + 256) / 256, 256, 0, stream>>>(deg, pos, N);

    gat_gemm_mfma<<<(N + 63) / 64, 256, 0, stream>>>(X, W1, b1, W2, b2, wa1, ba1, wa2, ba2,
                                                     (float*)d_out, fjb, a1, a2, N);

    gat_hist<<<1024, 256, 0, stream>>>(ei, deg, E, N, flags);
    gat_scan<<<1, 256, 0, stream>>>(deg, offs, N);
    gat_bucket<<<1024, 256, 0, stream>>>(ei, offs, pos, colPerm, E, N, flags);

    gat_accum<<<(N * 64 + 255) / 256, 256, 0, stream>>>(offs, colPerm, a1, a2, fjb,
                                                        (float*)d_out, N);
}

// Round 5
// 258.409 us; speedup vs baseline: 2.2670x; 1.2246x over previous
//
#include <hip/hip_runtime.h>
#include <hip/hip_bf16.h>

#define DD 128
#define SCAN_CHUNK 2048   // elements per block in scanA/C

typedef __bf16 bf16x8 __attribute__((ext_vector_type(8)));
typedef unsigned short u16x8 __attribute__((ext_vector_type(8)));
typedef float f32x4 __attribute__((ext_vector_type(4)));

__device__ __forceinline__ float lo16(unsigned int d) {
    union { unsigned int i; float f; } v; v.i = d << 16; return v.f;
}
__device__ __forceinline__ float hi16(unsigned int d) {
    union { unsigned int i; float f; } v; v.i = d & 0xffff0000u; return v.f;
}
__device__ __forceinline__ unsigned short f2bf(float f) {
    union { float f; unsigned int i; } v; v.f = f;
    unsigned int x = v.i;
    return (unsigned short)((x + 0x7fffu + ((x >> 16) & 1u)) >> 16);  // RNE
}

// ---------------------------------------------------------------------------
// Kernel 0: sniff edge-index width. flags[1]=1 if int64 (odd dwords all 0).
// ---------------------------------------------------------------------------
__global__ void gat_sniff(const unsigned int* __restrict__ EI, int* __restrict__ flags)
{
    const int lane = threadIdx.x;
    const int vote_i64 = (EI[2 * lane + 1] == 0u) ? 1 : 0;
    unsigned long long mi = __ballot(vote_i64);
    if (lane == 0) flags[1] = (__popcll(mi) == 64) ? 1 : 0;
}

__global__ __launch_bounds__(256)
void gat_zero(int* __restrict__ deg, int* __restrict__ pos, int N)
{
    const int i = blockIdx.x * blockDim.x + threadIdx.x;
    if (i <= N) deg[i] = 0;
    if (i < N)  pos[i] = 0;
}

// ---------------------------------------------------------------------------
// MFMA GEMM: one block = 64 rows x 256 cols (fi|fj), K=128, bf16 inputs.
// ---------------------------------------------------------------------------
__global__ __launch_bounds__(256)
void gat_gemm_mfma(const float* __restrict__ X,
                   const float* __restrict__ W1, const float* __restrict__ b1,
                   const float* __restrict__ W2, const float* __restrict__ b2,
                   const float* __restrict__ wa1, const float* __restrict__ ba1,
                   const float* __restrict__ wa2, const float* __restrict__ ba2,
                   float* __restrict__ out, unsigned int* __restrict__ fjb,
                   float* __restrict__ a1g, float* __restrict__ a2g, int N)
{
    const int t = threadIdx.x, wave = t >> 6, lane = t & 63;
    const int quad = lane >> 4, l15 = lane & 15;
    const int rowbase = blockIdx.x * 64;

    __shared__ unsigned short At[64 * 136];   // bf16, padded stride
    __shared__ float fjL[64 * 132];           // fj fp32, padded
    __shared__ float parts[4][64];
    __shared__ float attL[64];

    const float bab1 = *ba1, bab2 = *ba2;

    // ---- B preload: 16 frags, stays in VGPRs ----
    bf16x8 bf[4][4];
    float biasv[4], attwv[4];
#pragma unroll
    for (int ct = 0; ct < 4; ++ct) {
        const int n = wave * 64 + ct * 16 + l15;
        const float* wr = (n < 128) ? (W1 + (size_t)n * 128) : (W2 + (size_t)(n - 128) * 128);
        biasv[ct] = (n < 128) ? b1[n] : b2[n - 128];
        attwv[ct] = (n < 128) ? wa1[n] : wa2[n - 128];
#pragma unroll
        for (int ks = 0; ks < 4; ++ks) {
            const int k0 = ks * 32 + quad * 8;
            const float4 u = *(const float4*)(wr + k0);
            const float4 v = *(const float4*)(wr + k0 + 4);
            u16x8 s;
            s[0] = f2bf(u.x); s[1] = f2bf(u.y); s[2] = f2bf(u.z); s[3] = f2bf(u.w);
            s[4] = f2bf(v.x); s[5] = f2bf(v.y); s[6] = f2bf(v.z); s[7] = f2bf(v.w);
            bf[ct][ks] = __builtin_bit_cast(bf16x8, s);
        }
    }

    // ---- stage A-tile: X fp32 -> bf16 LDS ----
    {
        const int r = t >> 2, q = t & 3;
        const int grow = rowbase + r;
#pragma unroll
        for (int i = 0; i < 8; ++i) {
            const int c = q * 32 + i * 4;
            float4 xv = make_float4(0.f, 0.f, 0.f, 0.f);
            if (grow < N) xv = *(const float4*)(X + (size_t)grow * DD + c);
            uint2 p;
            p.x = ((unsigned)f2bf(xv.y) << 16) | f2bf(xv.x);
            p.y = ((unsigned)f2bf(xv.w) << 16) | f2bf(xv.z);
            *(uint2*)&At[r * 136 + c] = p;
        }
    }
    __syncthreads();

    // ---- MFMA main ----
    f32x4 acc[4][4];
#pragma unroll
    for (int rt = 0; rt < 4; ++rt)
#pragma unroll
        for (int ct = 0; ct < 4; ++ct)
            acc[rt][ct] = (f32x4){0.f, 0.f, 0.f, 0.f};

#pragma unroll
    for (int ks = 0; ks < 4; ++ks) {
#pragma unroll
        for (int rt = 0; rt < 4; ++rt) {
            const bf16x8 af = *(const bf16x8*)&At[(rt * 16 + l15) * 136 + ks * 32 + quad * 8];
#pragma unroll
            for (int ct = 0; ct < 4; ++ct)
                acc[rt][ct] = __builtin_amdgcn_mfma_f32_16x16x32_bf16(af, bf[ct][ks], acc[rt][ct], 0, 0, 0);
        }
    }

    // ---- bias + relu ----
#pragma unroll
    for (int rt = 0; rt < 4; ++rt)
#pragma unroll
        for (int ct = 0; ct < 4; ++ct)
#pragma unroll
            for (int reg = 0; reg < 4; ++reg) {
                float v = acc[rt][ct][reg] + biasv[ct];
                acc[rt][ct][reg] = v > 0.f ? v : 0.f;
            }

    if (wave >= 2) {
#pragma unroll
        for (int rt = 0; rt < 4; ++rt)
#pragma unroll
            for (int ct = 0; ct < 4; ++ct)
#pragma unroll
                for (int reg = 0; reg < 4; ++reg) {
                    const int row = rt * 16 + quad * 4 + reg;
                    const int col = (wave - 2) * 64 + ct * 16 + l15;
                    fjL[row * 132 + col] = acc[rt][ct][reg];
                }
    }

#pragma unroll
    for (int rt = 0; rt < 4; ++rt) {
#pragma unroll
        for (int reg = 0; reg < 4; ++reg) {
            float p = acc[rt][0][reg] * attwv[0] + acc[rt][1][reg] * attwv[1]
                    + acc[rt][2][reg] * attwv[2] + acc[rt][3][reg] * attwv[3];
            p += __shfl_xor(p, 1);
            p += __shfl_xor(p, 2);
            p += __shfl_xor(p, 4);
            p += __shfl_xor(p, 8);
            if (l15 == 0) parts[wave][rt * 16 + quad * 4 + reg] = p;
        }
    }
    __syncthreads();

    if (t < 64) {
        const float A1 = parts[0][t] + parts[1][t] + bab1;
        const float A2 = parts[2][t] + parts[3][t] + bab2;
        attL[t] = 1.f / (1.f + expf(-(A1 + A2)));
        const int grow = rowbase + t;
        if (grow < N) { a1g[grow] = A1; a2g[grow] = A2; }
    }
    __syncthreads();

    if (wave < 2) {
#pragma unroll
        for (int rt = 0; rt < 4; ++rt)
#pragma unroll
            for (int ct = 0; ct < 4; ++ct)
#pragma unroll
                for (int reg = 0; reg < 4; ++reg) {
                    const int row = rt * 16 + quad * 4 + reg;
                    const int col = wave * 64 + ct * 16 + l15;
                    const int grow = rowbase + row;
                    if (grow < N)
                        out[(size_t)grow * DD + col] =
                            acc[rt][ct][reg] + attL[row] * fjL[row * 132 + col];
                }
    } else {
#pragma unroll 4
        for (int i = 0; i < 32; ++i) {
            const int idx = (wave - 2) * 2048 + i * 64 + lane;
            const int row = idx >> 6, d = idx & 63;
            const int grow = rowbase + row;
            if (grow < N) {
                const float lo = fjL[row * 132 + 2 * d];
                const float hi = fjL[row * 132 + 2 * d + 1];
                fjb[(size_t)grow * 64 + d] = ((unsigned)f2bf(hi) << 16) | f2bf(lo);
            }
        }
    }
}

// ---------------------------------------------------------------------------
// CSR build
// ---------------------------------------------------------------------------
__global__ __launch_bounds__(256)
void gat_hist(const int* __restrict__ ei, int* __restrict__ deg,
              int nEdges, int N, const int* __restrict__ flags)
{
    const int i64 = flags[1];
    const int tid = blockIdx.x * blockDim.x + threadIdx.x;
    const int nth = gridDim.x * blockDim.x;
    for (int e = tid; e < nEdges; e += nth) {
        int r = i64 ? ei[2 * e] : ei[e];
        if ((unsigned)r >= (unsigned)N) r = 0;
        atomicAdd(&deg[r], 1);
    }
}

// ---- two-level scan: A) per-block local excl scan + block sums ------------
__global__ __launch_bounds__(256)
void gat_scanA(const int* __restrict__ deg, int* __restrict__ offs,
               int* __restrict__ blkSum, int N)
{
    __shared__ int wsum[4];
    const int t = threadIdx.x, lane = t & 63, wv = t >> 6;
    const int base = blockIdx.x * SCAN_CHUNK;
    const int idx0 = base + t * 8;
    int v[8];
#pragma unroll
    for (int i = 0; i < 8; ++i) {
        const int idx = idx0 + i;
        v[i] = (idx < N) ? deg[idx] : 0;
    }
    int s = 0;
#pragma unroll
    for (int i = 0; i < 8; ++i) s += v[i];
    int sc = s;
#pragma unroll
    for (int off = 1; off < 64; off <<= 1) {
        const int o = __shfl_up(sc, off);
        if (lane >= off) sc += o;
    }
    if (lane == 63) wsum[wv] = sc;
    __syncthreads();
    int wpre = 0;
    for (int i = 0; i < wv; ++i) wpre += wsum[i];
    int run = wpre + (sc - s);
#pragma unroll
    for (int i = 0; i < 8; ++i) {
        const int idx = idx0 + i;
        if (idx < N) offs[idx] = run;
        run += v[i];
    }
    if (t == 0) blkSum[blockIdx.x] = wsum[0] + wsum[1] + wsum[2] + wsum[3];
}

// ---- B) single-block excl scan of block sums (nBlk <= 2048) ---------------
__global__ __launch_bounds__(256)
void gat_scanB(int* __restrict__ blkSum, int* __restrict__ offsN, int nBlk)
{
    __shared__ int wsum[4];
    const int t = threadIdx.x, lane = t & 63, wv = t >> 6;
    const int idx0 = t * 8;
    int v[8];
#pragma unroll
    for (int i = 0; i < 8; ++i) {
        const int idx = idx0 + i;
        v[i] = (idx < nBlk) ? blkSum[idx] : 0;
    }
    int s = 0;
#pragma unroll
    for (int i = 0; i < 8; ++i) s += v[i];
    int sc = s;
#pragma unroll
    for (int off = 1; off < 64; off <<= 1) {
        const int o = __shfl_up(sc, off);
        if (lane >= off) sc += o;
    }
    if (lane == 63) wsum[wv] = sc;
    __syncthreads();
    int wpre = 0;
    for (int i = 0; i < wv; ++i) wpre += wsum[i];
    int run = wpre + (sc - s);
#pragma unroll
    for (int i = 0; i < 8; ++i) {
        const int idx = idx0 + i;
        if (idx < nBlk) blkSum[idx] = run;
        run += v[i];
    }
    if (t == 255) *offsN = run;   // grand total -> offs[N]
}

// ---- C) uniform add of block prefix ---------------------------------------
__global__ __launch_bounds__(256)
void gat_scanC(int* __restrict__ offs, const int* __restrict__ blkSum, int N)
{
    const int base = blockIdx.x * SCAN_CHUNK;
    const int add  = blkSum[blockIdx.x];
    const int idx0 = base + threadIdx.x * 8;
#pragma unroll
    for (int i = 0; i < 8; ++i) {
        const int idx = idx0 + i;
        if (idx < N) offs[idx] += add;
    }
}

// ---------------------------------------------------------------------------
// Bucket: CSR order, store (col, att) per edge. att computed here (idle VALU
// under atomic latency) so accum's chain is one gather deep.
// ---------------------------------------------------------------------------
__global__ __launch_bounds__(256)
void gat_bucket(const int* __restrict__ ei, const int* __restrict__ offs,
                int* __restrict__ pos, uint2* __restrict__ edges,
                const float* __restrict__ a1, const float* __restrict__ a2,
                int nEdges, int N, const int* __restrict__ flags)
{
    const int i64 = flags[1];
    const int tid = blockIdx.x * blockDim.x + threadIdx.x;
    const int nth = gridDim.x * blockDim.x;
    for (int e = tid; e < nEdges; e += nth) {
        int r = i64 ? ei[2 * e]            : ei[e];
        int c = i64 ? ei[2 * (nEdges + e)] : ei[nEdges + e];
        if ((unsigned)r >= (unsigned)N) r = 0;
        if ((unsigned)c >= (unsigned)N) c = 0;
        const float att = 1.f / (1.f + expf(-(a1[r] + a2[c])));
        const int slot = offs[r] + atomicAdd(&pos[r], 1);
        edges[slot] = make_uint2((unsigned)c, __float_as_uint(att));
    }
}

// ---------------------------------------------------------------------------
// Accumulate: one wave per row, 8 gathers in flight, no transcendentals.
// ---------------------------------------------------------------------------
__global__ __launch_bounds__(256)
void gat_accum(const int* __restrict__ offs, const uint2* __restrict__ edges,
               const unsigned int* __restrict__ fjb, float* __restrict__ out, int N)
{
    const int lane = threadIdx.x & 63;
    const int row  = (blockIdx.x * blockDim.x + threadIdx.x) >> 6;
    if (row >= N) return;

    const int start = offs[row], end = offs[row + 1];
    float ax = 0.f, ay = 0.f;
    int e = start;
    for (; e + 8 <= end; e += 8) {
        uint2 p[8];
#pragma unroll
        for (int j = 0; j < 8; ++j) p[j] = edges[e + j];
        unsigned d[8];
#pragma unroll
        for (int j = 0; j < 8; ++j) d[j] = fjb[(size_t)p[j].x * 64 + lane];
#pragma unroll
        for (int j = 0; j < 8; ++j) {
            const float att = __uint_as_float(p[j].y);
            ax += att * lo16(d[j]);
            ay += att * hi16(d[j]);
        }
    }
    for (; e < end; ++e) {
        const uint2 p = edges[e];
        const float att = __uint_as_float(p.y);
        const unsigned d = fjb[(size_t)p.x * 64 + lane];
        ax += att * lo16(d);
        ay += att * hi16(d);
    }
    float2* op = (float2*)&out[(size_t)row * DD + 2 * lane];
    float2 cur = *op;
    cur.x += ax; cur.y += ay;
    *op = cur;
}

extern "C" void kernel_launch(void* const* d_in, const int* in_sizes, int n_in,
                              void* d_out, int out_size, void* d_ws, size_t ws_size,
                              hipStream_t stream)
{
    const float* X   = (const float*)d_in[0];
    const float* W1  = (const float*)d_in[1];
    const float* b1  = (const float*)d_in[2];
    const float* W2  = (const float*)d_in[3];
    const float* b2  = (const float*)d_in[4];
    const float* wa1 = (const float*)d_in[5];
    const float* ba1 = (const float*)d_in[6];
    const float* wa2 = (const float*)d_in[7];
    const float* ba2 = (const float*)d_in[8];
    const int*   ei  = (const int*)d_in[9];

    const int N = in_sizes[0] / DD;
    const int E = in_sizes[9] / 2;

    // ws: [flags 256B][fjb N*64 u32][edges E uint2][a1 N][a2 N][deg N+1][offs N+1][pos N][blkSum 2048]
    int*   flags = (int*)d_ws;
    char*  base  = (char*)d_ws + 256;
    unsigned int* fjb = (unsigned int*)base;
    uint2* edges = (uint2*)(base + (size_t)N * 64 * 4);
    float* a1    = (float*)((char*)edges + (size_t)E * 8);
    float* a2    = a1 + N;
    int*   deg   = (int*)(a2 + N);
    int*   offs  = deg + (N + 1);
    int*   pos   = offs + (N + 1);
    int*   blkSum = pos + N;

    gat_sniff<<<1, 64, 0, stream>>>((const unsigned int*)ei, flags);
    gat_zero<<<(N + 256) / 256, 256, 0, stream>>>(deg, pos, N);

    gat_gemm_mfma<<<(N + 63) / 64, 256, 0, stream>>>(X, W1, b1, W2, b2, wa1, ba1, wa2, ba2,
                                                     (float*)d_out, fjb, a1, a2, N);

    gat_hist<<<1024, 256, 0, stream>>>(ei, deg, E, N, flags);

    const int nBlkScan = (N + SCAN_CHUNK - 1) / SCAN_CHUNK;
    gat_scanA<<<nBlkScan, 256, 0, stream>>>(deg, offs, blkSum, N);
    gat_scanB<<<1, 256, 0, stream>>>(blkSum, offs + N, nBlkScan);
    gat_scanC<<<nBlkScan, 256, 0, stream>>>(offs, blkSum, N);

    gat_bucket<<<1024, 256, 0, stream>>>(ei, offs, pos, edges, a1, a2, E, N, flags);

    gat_accum<<<(N * 64 + 255) / 256, 256, 0, stream>>>(offs, edges, fjb,
                                                        (float*)d_out, N);
}